// Round 5
// baseline (511.192 us; speedup 1.0000x reference)
//
#include <hip/hip_runtime.h>
#include <hip/hip_bf16.h>
#include <math.h>

// ImageTokenization: conv3x3(64->64)+BN+GELU -> patches(masked) -> proj GEMM(2304->768)+GELU
// Inputs fp32, outputs fp32; compute bf16 MFMA. d_out = [tokens 8192x768][patches 8192x2304].
// R5: conv = 3-row halo, single barrier, 3 blocks/CU; conv writes bf16 A-copy for gemm
// (ws permitting, else cvt fallback); gemm BM128/BN96/BK64 = 512 blocks (2/CU exact);
// prep kernels merged.

typedef unsigned short u16;
typedef __bf16 bf16x8 __attribute__((ext_vector_type(8)));
typedef float f32x4 __attribute__((ext_vector_type(4)));

#define NFRM 32
#define CH 64
#define HW 96
#define HWP 98
#define KP 2304
#define DIMN 768
#define MTOK 8192
#define TOKN (MTOK * DIMN)
#define ABF_ELEMS ((size_t)MTOK * KP)                 // 18,874,368
#define XHWC_ELEMS ((size_t)NFRM * HWP * HWP * CH)    // 19,668,992

static __device__ __forceinline__ u16 f2b(float f) {
  unsigned u = __builtin_bit_cast(unsigned, f);
  u += 0x7fffu + ((u >> 16) & 1u);
  return (u16)(u >> 16);
}
static __device__ __forceinline__ float gelu_f(float x) {
  return 0.5f * x * (1.0f + erff(x * 0.7071067811865476f));
}

// -------- prep: halo-zero + NCHW->NHWC bf16 transpose + conv_w repack + proj_w cvt --------
#define PB_ZERO 388
#define PB_TR (PB_ZERO + 3072)
#define PB_BP (PB_TR + 144)
#define PB_PW (PB_BP + 1728)
__global__ __launch_bounds__(256) void k_prep(const float* __restrict__ x,
                                              const float* __restrict__ cw,
                                              const float* __restrict__ pwf,
                                              u16* __restrict__ xhwc,
                                              u16* __restrict__ bp,
                                              u16* __restrict__ pw) {
  __shared__ u16 tile[96 * 66];
  const int b = blockIdx.x, t = threadIdx.x;
  if (b < PB_ZERO) {  // zero 1-px halo border of xhwc
    int id = b * 256 + t;
    int p = id >> 3, cs = id & 7;
    int f = p / 388, bpx = p - f * 388;
    int h, w;
    if (bpx < 98) { h = 0; w = bpx; }
    else if (bpx < 196) { h = 97; w = bpx - 98; }
    else { int q = bpx - 196; h = 1 + (q >> 1); w = (q & 1) ? 97 : 0; }
    ushort4 z = {0, 0, 0, 0};
    *(ushort4*)(xhwc + ((size_t)(f * HWP + h) * HWP + w) * CH + cs * 8) = z;
  } else if (b < PB_TR) {  // transpose one (frame,row): fp32 NCHW -> bf16 NHWC interior
    int bt = b - PB_ZERO;
    const int f = bt / 96, h = bt % 96;
    const float* xp = x + (size_t)f * CH * HW * HW + (size_t)h * HW;
#pragma unroll
    for (int k = 0; k < 6; ++k) {
      int e = (k * 256 + t) * 4;
      int ci = e / 96, w = e % 96;
      float4 v = *(const float4*)(xp + (size_t)ci * (HW * HW) + w);
      tile[(w + 0) * 66 + ci] = f2b(v.x);
      tile[(w + 1) * 66 + ci] = f2b(v.y);
      tile[(w + 2) * 66 + ci] = f2b(v.z);
      tile[(w + 3) * 66 + ci] = f2b(v.w);
    }
    __syncthreads();
    u16* op = xhwc + ((size_t)(f * HWP + h + 1) * HWP + 1) * CH;
#pragma unroll
    for (int k = 0; k < 12; ++k) {
      int e2 = (k * 256 + t) * 2;
      int w = e2 >> 6, ci = e2 & 63;
      *(unsigned*)(op + e2) = *(const unsigned*)(&tile[w * 66 + ci]);
    }
  } else if (b < PB_BP) {  // conv_w[co][ci][3][3] -> bp[co][tap*64+ci]
    int e = (b - PB_TR) * 256 + t;  // < 36864
    int co = e / 576, r = e - co * 576, tap = r >> 6, ci = r & 63;
    bp[e] = f2b(cw[(co * 64 + ci) * 9 + tap]);
  } else {  // proj_w fp32 -> bf16
    int e = ((b - PB_BP) * 256 + t) * 4;  // < 1,769,472
    float4 v = *(const float4*)(pwf + e);
    ushort4 o;
    o.x = f2b(v.x); o.y = f2b(v.y); o.z = f2b(v.z); o.w = f2b(v.w);
    *(ushort4*)(pw + e) = o;
  }
}

// -------- conv: 3-row halo in LDS, single barrier, one output row per block --------
// Block: (frame f, row h). M=96 px, N=64 co, K=9taps*64ci. Waves 2M x 2N.
template <bool WRITE_ABF>
__global__ __launch_bounds__(256) void k_conv(
    const u16* __restrict__ xhwc, const u16* __restrict__ bw,
    const float* __restrict__ cb, const float* __restrict__ gma,
    const float* __restrict__ bta, const float* __restrict__ mu,
    const float* __restrict__ var, const float* __restrict__ msk,
    float* __restrict__ pout, u16* __restrict__ abf) {
  __shared__ u16 halo[3 * 98 * 72];  // 42.3 KB -> 3 blocks/CU
  const int f = blockIdx.x / 96;
  const int h = blockIdx.x % 96;
  const int t = threadIdx.x;
  const int wv = t >> 6, l = t & 63, quad = l >> 4, lm = l & 15;
  const int mhalf = wv & 1, nhalf = wv >> 1;
  const u16* xf = xhwc + (size_t)f * (HWP * HWP * CH);

  // stage xhwc rows h..h+2, 98 px, 64 ci (2352 uint4 chunks)
#pragma unroll
  for (int it = 0; it < 10; ++it) {
    int c = it * 256 + t;
    if (c < 2352) {
      int hr = c / 784, rem = c - hr * 784;
      int w = rem >> 3, cs = rem & 7;
      *(uint4*)(halo + (hr * 98 + w) * 72 + cs * 8) =
          *(const uint4*)(xf + ((size_t)(h + hr) * HWP + w) * CH + cs * 8);
    }
  }
  __syncthreads();  // the only barrier

  const int wbase = mhalf * 48;
  f32x4 acc[3][2];
#pragma unroll
  for (int mt = 0; mt < 3; ++mt)
#pragma unroll
    for (int u = 0; u < 2; ++u) acc[mt][u] = (f32x4){0.f, 0.f, 0.f, 0.f};

#pragma unroll
  for (int tap = 0; tap < 9; ++tap) {
    const int di = tap / 3, dj = tap - di * 3;
    bf16x8 bfr[2][2];
#pragma unroll
    for (int ks = 0; ks < 2; ++ks)
#pragma unroll
      for (int u = 0; u < 2; ++u)
        bfr[ks][u] = *(const bf16x8*)(bw + (nhalf * 32 + u * 16 + lm) * 576 +
                                      tap * 64 + ks * 32 + quad * 8);
#pragma unroll
    for (int mt = 0; mt < 3; ++mt) {
      const int base = (di * 98 + wbase + mt * 16 + lm + dj) * 72;
#pragma unroll
      for (int ks = 0; ks < 2; ++ks) {
        bf16x8 a = *(const bf16x8*)(halo + base + ks * 32 + quad * 8);
#pragma unroll
        for (int u = 0; u < 2; ++u)
          acc[mt][u] =
              __builtin_amdgcn_mfma_f32_16x16x32_bf16(a, bfr[ks][u], acc[mt][u], 0, 0, 0);
      }
    }
  }

  // epilogue: BN + GELU + mask; patch-ordered stores (fp32 + optional bf16 A-copy)
  const int hd = h / 6, hm = h - hd * 6;
#pragma unroll
  for (int u = 0; u < 2; ++u) {
    const int co = nhalf * 32 + u * 16 + lm;  // C/D col = lane&15
    const float scv = gma[co] * rsqrtf(var[co] + 1e-5f);
    const float b2v = (cb[co] - mu[co]) * scv + bta[co];
#pragma unroll
    for (int mt = 0; mt < 3; ++mt) {
#pragma unroll
      for (int rg = 0; rg < 4; ++rg) {
        const int wpx = wbase + mt * 16 + quad * 4 + rg;  // C/D row = quad*4+reg
        const int wd = wpx / 6, wm = wpx - wd * 6;
        const int ii = hm * 6 + wm;
        const size_t idx =
            (size_t)(f * 256 + hd * 16 + wd) * KP + co * 36 + ii;
        float v = acc[mt][u][rg] * scv + b2v;
        v = gelu_f(v) * msk[ii];
        pout[idx] = v;
        if (WRITE_ABF) abf[idx] = f2b(v);
      }
    }
  }
}

// -------- cvt fallback: patches fp32 -> A bf16 --------
__global__ __launch_bounds__(256) void k_cvt(const float* __restrict__ pat,
                                             u16* __restrict__ abf) {
  int e = (blockIdx.x * 256 + threadIdx.x) * 4;
  float4 v = *(const float4*)(pat + e);
  ushort4 o;
  o.x = f2b(v.x); o.y = f2b(v.y); o.z = f2b(v.z); o.w = f2b(v.w);
  *(ushort4*)(abf + e) = o;
}

// -------- gemm: tokens = gelu(A @ proj_w^T + proj_b) --------
// M=8192 K=2304 N=768; BM=128 BN=96 BK=64 -> 512 blocks (2/CU exact). Waves 2M x 2N.
__global__ __launch_bounds__(256) void k_gemm(const u16* __restrict__ A,
                                              const u16* __restrict__ Bt,
                                              const float* __restrict__ pb,
                                              float* __restrict__ out) {
  __shared__ u16 As[128 * 72];
  __shared__ u16 Bs[96 * 72];  // 32.3 KB total
  const int bm = blockIdx.x >> 3, bn = blockIdx.x & 7;  // bn-fastest: A-slab L2 reuse
  const int m0 = bm * 128, n0 = bn * 96;
  const int t = threadIdx.x, wv = t >> 6, l = t & 63, quad = l >> 4, lm = l & 15;
  const int wm = wv & 1, wn = wv >> 1;

  f32x4 acc[4][3];
#pragma unroll
  for (int mt = 0; mt < 4; ++mt)
#pragma unroll
    for (int ut = 0; ut < 3; ++ut) acc[mt][ut] = (f32x4){0.f, 0.f, 0.f, 0.f};

  for (int k0 = 0; k0 < KP; k0 += 64) {
    __syncthreads();
#pragma unroll
    for (int it = 0; it < 7; ++it) {  // 1024 A-chunks + 768 B-chunks = 7*256
      int c = it * 256 + t;
      if (c < 1024) {
        int row = c >> 3, cs = c & 7;
        *(uint4*)&As[row * 72 + cs * 8] =
            *(const uint4*)&A[(size_t)(m0 + row) * KP + k0 + cs * 8];
      } else {
        int c2 = c - 1024, row = c2 >> 3, cs = c2 & 7;
        *(uint4*)&Bs[row * 72 + cs * 8] =
            *(const uint4*)&Bt[(size_t)(n0 + row) * KP + k0 + cs * 8];
      }
    }
    __syncthreads();
#pragma unroll
    for (int ks = 0; ks < 2; ++ks) {
      bf16x8 af[4], bf[3];
#pragma unroll
      for (int mt = 0; mt < 4; ++mt)
        af[mt] = *(const bf16x8*)&As[(wm * 64 + mt * 16 + lm) * 72 + ks * 32 + quad * 8];
#pragma unroll
      for (int ut = 0; ut < 3; ++ut)
        bf[ut] = *(const bf16x8*)&Bs[(wn * 48 + ut * 16 + lm) * 72 + ks * 32 + quad * 8];
#pragma unroll
      for (int mt = 0; mt < 4; ++mt)
#pragma unroll
        for (int ut = 0; ut < 3; ++ut)
          acc[mt][ut] =
              __builtin_amdgcn_mfma_f32_16x16x32_bf16(af[mt], bf[ut], acc[mt][ut], 0, 0, 0);
    }
  }
#pragma unroll
  for (int ut = 0; ut < 3; ++ut) {
    const int n = n0 + wn * 48 + ut * 16 + lm;
    const float bias = pb[n];
#pragma unroll
    for (int mt = 0; mt < 4; ++mt)
#pragma unroll
      for (int rg = 0; rg < 4; ++rg) {
        const int m = m0 + wm * 64 + mt * 16 + quad * 4 + rg;
        out[(size_t)m * DIMN + n] = gelu_f(acc[mt][ut][rg] + bias);
      }
  }
}

extern "C" void kernel_launch(void* const* d_in, const int* in_sizes, int n_in,
                              void* d_out, int out_size, void* d_ws, size_t ws_size,
                              hipStream_t stream) {
  const float* x = (const float*)d_in[0];
  const float* conv_w = (const float*)d_in[1];
  const float* conv_b = (const float*)d_in[2];
  const float* bn_gamma = (const float*)d_in[3];
  const float* bn_beta = (const float*)d_in[4];
  const float* bn_mean = (const float*)d_in[5];
  const float* bn_var = (const float*)d_in[6];
  const float* proj_w = (const float*)d_in[7];
  const float* proj_b = (const float*)d_in[8];
  const float* mask = (const float*)d_in[9];
  float* out = (float*)d_out;
  float* patches = out + TOKN;
  u16* ws = (u16*)d_ws;

  const size_t need = (ABF_ELEMS + XHWC_ELEMS + 36864 + 1769472) * sizeof(u16);
  const bool direct = ws_size >= need;  // host-side, constant across calls

  u16 *abf, *xhwc, *bp, *pw;
  if (direct) {
    abf = ws;
    xhwc = ws + ABF_ELEMS;
  } else {
    xhwc = ws;
    abf = ws;  // aliased: xhwc dead after conv, cvt fills it
  }
  bp = xhwc + XHWC_ELEMS;
  pw = bp + 36864;

  k_prep<<<PB_PW, 256, 0, stream>>>(x, conv_w, proj_w, xhwc, bp, pw);
  if (direct) {
    k_conv<true><<<NFRM * 96, 256, 0, stream>>>(xhwc, bp, conv_b, bn_gamma, bn_beta,
                                                bn_mean, bn_var, mask, patches, abf);
  } else {
    k_conv<false><<<NFRM * 96, 256, 0, stream>>>(xhwc, bp, conv_b, bn_gamma, bn_beta,
                                                 bn_mean, bn_var, mask, patches, abf);
    k_cvt<<<18432, 256, 0, stream>>>(patches, abf);
  }
  k_gemm<<<64 * 8, 256, 0, stream>>>(abf, pw, proj_b, out);
}